// Round 14
// baseline (233.276 us; speedup 1.0000x reference)
//
#include <hip/hip_runtime.h>

// MFMA f16 conv pipeline, round 14.
// Round-13 post-mortem: conv2/3 32x32 switch neutral (232.6 vs 228.7) ->
// conv2/3 are stall-dominated like conv1, not matrix-pipe-bound. Apply the
// one proven structural win (round-11 rolling window) to conv2, and halve
// fc_head's L2-bound wl1 traffic by converting wl1 to f16 (pack_wl1).
//
// Layouts (CDNA4):
//   16x16x32: A/B k=(lane>>4)*8+j, m/n=lane&15; D col=lane&15, row=(lane>>4)*4+reg
//   32x32x16: A/B k=(lane>>5)*8+j, m/n=lane&31; D col=lane&31,
//             row=(reg&3)+8*(reg>>2)+4*(lane>>5)

typedef _Float16 f16;
typedef _Float16 f16x8 __attribute__((ext_vector_type(8)));
typedef _Float16 f16x4 __attribute__((ext_vector_type(4)));
typedef float f32x4 __attribute__((ext_vector_type(4)));
typedef float f32x16 __attribute__((ext_vector_type(16)));

// ---------------- weight pre-pack (conv weights -> A-fragment order) ----------
// frags (1024B = [lane][j] f16):
//   conv1 @0:  9  (32x32 A, ks=kh*3+kw)
//   conv2 @9:  36 (32x32 A, idx = (sh*2+ks)*2+ocg, ic = ks*16 + hi*8 + j)
//   conv3 @45: 72 (32x32 A, idx = (sh*4+ks)*2+ocg, ic = ks*16 + hi*8 + j)
//   conv4 @117:72 (16x16 A, idx = (sh*2+ks)*4+og,  ic = ks*32 + kg*8 + j)
__global__ __launch_bounds__(512)
void pack_weights(const float* __restrict__ w1, const float* __restrict__ w2,
                  const float* __restrict__ w3, const float* __restrict__ w4,
                  f16* __restrict__ apack) {
  int idx = blockIdx.x * 512 + threadIdx.x;   // 189*512 total
  int frag = idx >> 9;
  int e = idx & 511;
  int lane = e >> 3, j = e & 7;
  float v = 0.f;
  if (frag < 9) {
    int kh = frag / 3, kw = frag % 3;
    int oc = lane & 31;
    int ic = (lane >> 5) * 8 + j;
    if (ic < 12) v = w1[((oc * 12 + ic) * 3 + kh) * 3 + kw];
  } else if (frag < 45) {
    int f = frag - 9;            // conv2 32x32
    int ocg = f & 1;
    int sk = f >> 1;
    int ks = sk & 1, sh = sk >> 1;
    int kh = sh / 3, kw = sh % 3;
    int oc = ocg * 32 + (lane & 31);
    int ic = ks * 16 + (lane >> 5) * 8 + j;
    v = w2[((oc * 32 + ic) * 3 + kh) * 3 + kw];
  } else if (frag < 117) {
    int f = frag - 45;           // conv3 32x32
    int ocg = f & 1;
    int sk = f >> 1;
    int ks = sk & 3, sh = sk >> 2;
    int kh = sh / 3, kw = sh % 3;
    int oc = ocg * 32 + (lane & 31);
    int ic = ks * 16 + (lane >> 5) * 8 + j;
    v = w3[((oc * 64 + ic) * 3 + kh) * 3 + kw];
  } else {
    int f = frag - 117;          // conv4 16x16
    int sk = f >> 2, og = f & 3;
    int sh = sk >> 1, ks = sk & 1;
    int kh = sh / 3, kw = sh % 3;
    int row16 = lane & 15, kg = lane >> 4;
    int oc = og * 16 + row16;
    int ic = ks * 32 + kg * 8 + j;
    v = w4[((oc * 64 + ic) * 3 + kh) * 3 + kw];
  }
  apack[idx] = (f16)v;
}

// ---------------- wl1 fp32 -> f16 (halves fc_head's L2-bound traffic) ---------
__global__ __launch_bounds__(256)
void pack_wl1(const float* __restrict__ wl1, f16* __restrict__ wl1h) {
  int i = (blockIdx.x * 256 + threadIdx.x) * 4;   // 512 blocks, 524288 elems
  float4 v = *(const float4*)(wl1 + i);
  f16x4 h = { (f16)v.x, (f16)v.y, (f16)v.z, (f16)v.w };
  *(f16x4*)(wl1h + i) = h;
}

// ---------------- conv1: 12ch fp32 NCHW -> 32ch NHWC f16, pool ----------------
// (unchanged from round 12/13: TPB=8 rolling 6-slot window, 32x32x16, kw-outer)
__global__ __launch_bounds__(512)
void conv1_mfma(const float* __restrict__ x, const f16* __restrict__ apack,
                const float* __restrict__ bias, f16* __restrict__ hout) {
  constexpr int W = 128, H = 128;
  constexpr int PADB = 48, ROWB = 130 * PADB;   // 6240 B/row-slot
  constexpr int TPB = 8;
  __shared__ char smem[6 * ROWB];               // 37440 B
  const int tid = threadIdx.x;
  const int n = blockIdx.y;
  const int R0 = blockIdx.x * (TPB * 4);

  if (tid < 36) {
    int slot = tid / 6, r = tid % 6;
    int px = (r >= 3) ? 129 : 0;
    int ch = r % 3;
    *(float4*)(smem + slot * ROWB + px * PADB + ch * 16) =
        make_float4(0.f, 0.f, 0.f, 0.f);
  }

  const int g = tid >> 4;
  const int l16 = tid & 15;
  const int Q = l16 >> 2, q = l16 & 3;

  auto load_row = [&](int ri) -> float4 {
    float4 v = make_float4(0.f, 0.f, 0.f, 0.f);
    if (l16 < 12 && ri >= 0 && ri < H)
      v = *(const float4*)(x + ((size_t)(n * 12 + l16) * H + ri) * W + g * 4);
    return v;
  };
  auto xpose_write = [&](float4 av, int slot) {
    float4 t1, t2;
    {
      float sx = __shfl_xor(av.x, 1), sy = __shfl_xor(av.y, 1);
      float sz = __shfl_xor(av.z, 1), sw = __shfl_xor(av.w, 1);
      bool odd = q & 1;
      t1.x = odd ? sy : av.x;  t1.y = odd ? av.y : sx;
      t1.z = odd ? sw : av.z;  t1.w = odd ? av.w : sz;
    }
    {
      float sx = __shfl_xor(t1.x, 2), sy = __shfl_xor(t1.y, 2);
      float sz = __shfl_xor(t1.z, 2), sw = __shfl_xor(t1.w, 2);
      bool hi2 = q & 2;
      t2.x = hi2 ? sz : t1.x;  t2.y = hi2 ? sw : t1.y;
      t2.z = hi2 ? t1.z : sx;  t2.w = hi2 ? t1.w : sy;
    }
    f16x4 h = { (f16)t2.x, (f16)t2.y, (f16)t2.z, (f16)t2.w };
    *(f16x4*)(smem + slot * ROWB + (g * 4 + q + 1) * PADB + Q * 8) = h;
  };

  const int wv = tid >> 6, l = tid & 63;
  const int rp = wv >> 2;
  const int pxb = (wv & 3) * 32;
  const int rl0 = rp * 2;
  const int ln = l & 31;
  const int hi = l >> 5;

  f16x8 A[9];
#pragma unroll
  for (int ks = 0; ks < 9; ++ks)
    A[ks] = *(const f16x8*)(apack + ((ks << 9) + (l << 3)));

  float4 a[6];
#pragma unroll
  for (int i = 0; i < 6; ++i) a[i] = load_row(R0 - 1 + i);
#pragma unroll
  for (int i = 0; i < 6; ++i) xpose_write(a[i], i);
  __syncthreads();

  int s0 = 0;
  for (int t = 0; t < TPB; ++t) {
    if (t + 1 < TPB) {
#pragma unroll
      for (int i = 0; i < 4; ++i) a[i] = load_row(R0 + 4 * t + 5 + i);
    }
    f32x16 acc0 = (f32x16)0.f, acc1 = (f32x16)0.f;
#pragma unroll
    for (int kw = 0; kw < 3; ++kw) {
      const char* bcol = smem + (pxb + ln + kw) * PADB + hi * 16;
      f16x8 R[4];
#pragma unroll
      for (int j = 0; j < 4; ++j) {
        int sl = s0 + rl0 + j; if (sl >= 6) sl -= 6;
        R[j] = *(const f16x8*)(bcol + sl * ROWB);
      }
#pragma unroll
      for (int kh = 0; kh < 3; ++kh) {
        acc0 = __builtin_amdgcn_mfma_f32_32x32x16_f16(A[kh * 3 + kw], R[kh],     acc0, 0, 0, 0);
        acc1 = __builtin_amdgcn_mfma_f32_32x32x16_f16(A[kh * 3 + kw], R[kh + 1], acc1, 0, 0, 0);
      }
    }
    {
      const int pr = (R0 >> 1) + 2 * t + rp;
#pragma unroll
      for (int gg = 0; gg < 4; ++gg) {
        float v[4];
#pragma unroll
        for (int c = 0; c < 4; ++c) {
          float m = fmaxf(acc0[gg * 4 + c], acc1[gg * 4 + c]);
          v[c] = fmaxf(m, __shfl_xor(m, 1));
        }
        if ((l & 1) == 0) {
          const int pw = (pxb + ln) >> 1;
          const int oc0 = gg * 8 + hi * 4;
          f16x4 pk;
#pragma unroll
          for (int c = 0; c < 4; ++c)
            pk[c] = (f16)fmaxf(v[c] + bias[oc0 + c], 0.f);
          *(f16x4*)(hout + (((size_t)(n * 64 + pr) * 64 + pw) * 32 + oc0)) = pk;
        }
      }
    }
    __syncthreads();
    if (t + 1 < TPB) {
#pragma unroll
      for (int i = 0; i < 4; ++i) {
        int sl = s0 + i; if (sl >= 6) sl -= 6;
        xpose_write(a[i], sl);
      }
      __syncthreads();
    }
    s0 += 4; if (s0 >= 6) s0 -= 6;
  }
}

// ---------------- conv2: rolling-window multi-tile, 32x32x16 ------------------
// Block: TPB=4 tiles of (4 conv rows x 64 px), 256 thr, 6-slot mod-6 window.
// Steady state stages 4 rows/tile; loads(t+1) issue before compute(t).
__global__ __launch_bounds__(256)
void conv2_roll(const f16* __restrict__ hin, const f16* __restrict__ apack,
                const float* __restrict__ bias, f16* __restrict__ hout) {
  constexpr int C = 32, W = 64, H = 64;
  constexpr int PADB = 80, ROWB = 66 * PADB;    // 5280 B/row-slot
  constexpr int TPB = 4;
  __shared__ char smem[6 * ROWB];               // 31680 B
  const int tid = threadIdx.x;
  const int n = blockIdx.y;
  const int R0 = blockIdx.x * (TPB * 4);

  // chunk c of a row-batch: rowl = c/264, px = (c%264)>>2, kc = (c%264)&3
  auto chunk_ld = [&](int c, int rbase) -> float4 {
    int rowl = c / 264, rem = c - rowl * 264;
    int px = rem >> 2, kc = rem & 3;
    int ri = rbase + rowl, gx = px - 1;
    float4 v = make_float4(0.f, 0.f, 0.f, 0.f);
    if (ri >= 0 && ri < H && gx >= 0 && gx < W)
      v = *(const float4*)(hin + (((size_t)(n * H + ri) * W + gx) * C + kc * 8));
    return v;
  };
  auto chunk_st = [&](int c, int sbase, float4 v) {
    int rowl = c / 264, rem = c - rowl * 264;
    int px = rem >> 2, kc = rem & 3;
    int slot = sbase + rowl; if (slot >= 6) slot -= 6;
    *(float4*)(smem + slot * ROWB + px * PADB + kc * 16) = v;
  };

  // prologue: rows R0-1 .. R0+4 -> slots 0..5 (1584 chunks)
  {
    float4 a[7];
#pragma unroll
    for (int it = 0; it < 7; ++it) {
      int c = tid + it * 256;
      a[it] = (c < 1584) ? chunk_ld(c, R0 - 1) : make_float4(0.f, 0.f, 0.f, 0.f);
    }
#pragma unroll
    for (int it = 0; it < 7; ++it) {
      int c = tid + it * 256;
      if (c < 1584) chunk_st(c, 0, a[it]);
    }
  }
  __syncthreads();

  const int wv = tid >> 6, l = tid & 63;
  const int rp = wv >> 1;                // pooled row within tile (0..1)
  const int pxb = (wv & 1) * 32;
  const int rl0 = rp * 2;
  const int ln = l & 31;
  const int hi = l >> 5;

  float4 a[5];
  int s04 = 0;                           // (4t) % 6
  for (int t = 0; t < TPB; ++t) {
    if (t + 1 < TPB) {                   // issue next-tile loads early
#pragma unroll
      for (int it = 0; it < 5; ++it) {
        int c = tid + it * 256;
        a[it] = (c < 1056) ? chunk_ld(c, R0 + 4 * t + 5)
                           : make_float4(0.f, 0.f, 0.f, 0.f);
      }
    }
    // compute tile t
    f32x16 acc[2][2];
    acc[0][0] = (f32x16)0.f; acc[0][1] = (f32x16)0.f;
    acc[1][0] = (f32x16)0.f; acc[1][1] = (f32x16)0.f;
#pragma unroll
    for (int sh = 0; sh < 9; ++sh) {
      const int kh = sh / 3, kw = sh % 3;
      f16x8 A[2][2];
#pragma unroll
      for (int ks = 0; ks < 2; ++ks)
#pragma unroll
        for (int ocg = 0; ocg < 2; ++ocg)
          A[ks][ocg] = *(const f16x8*)(apack + ((((sh * 2 + ks) * 2 + ocg) << 9) + (l << 3)));
#pragma unroll
      for (int rowi = 0; rowi < 2; ++rowi) {
        int sl = s04 + rl0 + rowi + kh; if (sl >= 6) sl -= 6;   // max 9 -> ok
        const char* base = smem + sl * ROWB + (pxb + ln + kw) * PADB + hi * 16;
#pragma unroll
        for (int ks = 0; ks < 2; ++ks) {
          f16x8 B = *(const f16x8*)(base + ks * 32);
          acc[rowi][0] = __builtin_amdgcn_mfma_f32_32x32x16_f16(A[ks][0], B, acc[rowi][0], 0, 0, 0);
          acc[rowi][1] = __builtin_amdgcn_mfma_f32_32x32x16_f16(A[ks][1], B, acc[rowi][1], 0, 0, 0);
        }
      }
    }
    // epilogue: pool 2x2, bias, relu, NHWC store (OC=64)
    {
      const int pr = (R0 >> 1) + 2 * t + rp;
#pragma unroll
      for (int ocg = 0; ocg < 2; ++ocg) {
#pragma unroll
        for (int gg = 0; gg < 4; ++gg) {
          float v[4];
#pragma unroll
          for (int c = 0; c < 4; ++c) {
            float m = fmaxf(acc[0][ocg][gg * 4 + c], acc[1][ocg][gg * 4 + c]);
            v[c] = fmaxf(m, __shfl_xor(m, 1));
          }
          if ((l & 1) == 0) {
            const int pw = (pxb + ln) >> 1;
            const int oc0 = ocg * 32 + gg * 8 + hi * 4;
            f16x4 pk;
#pragma unroll
            for (int c = 0; c < 4; ++c)
              pk[c] = (f16)fmaxf(v[c] + bias[oc0 + c], 0.f);
            *(f16x4*)(hout + (((size_t)(n * 32 + pr) * 32 + pw) * 64 + oc0)) = pk;
          }
        }
      }
    }
    __syncthreads();
    if (t + 1 < TPB) {                   // overwrite slots s04..s04+3
#pragma unroll
      for (int it = 0; it < 5; ++it) {
        int c = tid + it * 256;
        if (c < 1056) chunk_st(c, s04, a[it]);
      }
      __syncthreads();
    }
    s04 += 4; if (s04 >= 6) s04 -= 6;
  }
}

// ---------------- conv3: one-shot 32x32x16 (unchanged from round 13) ----------
template<int C, int W, int H, int BR, int PADB>
__global__ __launch_bounds__(256)
void conv_shift32(const f16* __restrict__ hin, const f16* __restrict__ apack,
                  const float* __restrict__ bias, f16* __restrict__ hout) {
  constexpr int KS16 = C / 16;
  constexpr int SR = BR + 2;
  constexpr int ROWB = (W + 2) * PADB;
  __shared__ char smem[SR * ROWB];
  const int tid = threadIdx.x;
  const int n = blockIdx.y;
  const int r0 = blockIdx.x * BR;
  constexpr int CPC = C / 8;
  constexpr int TOTC = SR * (W + 2) * CPC;
  constexpr int NITER = (TOTC + 255) / 256;
  {
    float4 stg[NITER];
#pragma unroll
    for (int it = 0; it < NITER; ++it) {
      const int t = tid + it * 256;
      float4 v = make_float4(0.f, 0.f, 0.f, 0.f);
      if (t < TOTC) {
        int sr = t / ((W + 2) * CPC);
        int rem = t - sr * ((W + 2) * CPC);
        int px = rem / CPC;
        int kc = rem - px * CPC;
        int ri = r0 + sr - 1;
        int gx = px - 1;
        if (ri >= 0 && ri < H && gx >= 0 && gx < W)
          v = *(const float4*)(hin + (((size_t)(n * H + ri) * W + gx) * C + kc * 8));
      }
      stg[it] = v;
    }
#pragma unroll
    for (int it = 0; it < NITER; ++it) {
      const int t = tid + it * 256;
      if (t < TOTC) {
        int sr = t / ((W + 2) * CPC);
        int rem = t - sr * ((W + 2) * CPC);
        int px = rem / CPC;
        int kc = rem - px * CPC;
        *(float4*)(smem + sr * ROWB + px * PADB + kc * 16) = stg[it];
      }
    }
  }
  __syncthreads();

  const int wv = tid >> 6, l = tid & 63;
  constexpr int WPP = W / 32;
  const int rp = wv / WPP;
  const int pxb = (wv % WPP) * 32;
  const int rl0 = rp * 2;
  const int ln = l & 31;
  const int hi = l >> 5;
  const int px0 = pxb + ln;

  f32x16 acc[2][2];
  acc[0][0] = (f32x16)0.f; acc[0][1] = (f32x16)0.f;
  acc[1][0] = (f32x16)0.f; acc[1][1] = (f32x16)0.f;

#pragma unroll
  for (int sh = 0; sh < 9; ++sh) {
    const int kh = sh / 3, kw = sh % 3;
    f16x8 A[KS16][2];
#pragma unroll
    for (int ks = 0; ks < KS16; ++ks)
#pragma unroll
      for (int ocg = 0; ocg < 2; ++ocg)
        A[ks][ocg] = *(const f16x8*)(apack + ((((sh * KS16 + ks) * 2 + ocg) << 9) + (l << 3)));
#pragma unroll
    for (int rowi = 0; rowi < 2; ++rowi) {
      const char* base = smem + (rl0 + rowi + kh) * ROWB + (px0 + kw) * PADB + hi * 16;
#pragma unroll
      for (int ks = 0; ks < KS16; ++ks) {
        f16x8 B = *(const f16x8*)(base + ks * 32);
        acc[rowi][0] = __builtin_amdgcn_mfma_f32_32x32x16_f16(A[ks][0], B, acc[rowi][0], 0, 0, 0);
        acc[rowi][1] = __builtin_amdgcn_mfma_f32_32x32x16_f16(A[ks][1], B, acc[rowi][1], 0, 0, 0);
      }
    }
  }
  constexpr int PH = H / 2, PW = W / 2;
  const int pr = blockIdx.x * (BR / 2) + rp;
#pragma unroll
  for (int ocg = 0; ocg < 2; ++ocg) {
#pragma unroll
    for (int gg = 0; gg < 4; ++gg) {
      float v[4];
#pragma unroll
      for (int c = 0; c < 4; ++c) {
        float m = fmaxf(acc[0][ocg][gg * 4 + c], acc[1][ocg][gg * 4 + c]);
        v[c] = fmaxf(m, __shfl_xor(m, 1));
      }
      if ((l & 1) == 0) {
        const int pw = (pxb + ln) >> 1;
        const int oc0 = ocg * 32 + gg * 8 + hi * 4;
        f16x4 pk;
#pragma unroll
        for (int c = 0; c < 4; ++c)
          pk[c] = (f16)fmaxf(v[c] + bias[oc0 + c], 0.f);
        *(f16x4*)(hout + (((size_t)(n * PH + pr) * PW + pw) * 64 + oc0)) = pk;
      }
    }
  }
}

// ---------------- conv4: NHWC f16 -> NCHW f32, pool (16x16x32) ----------------
template<int C, int W, int H, int BR, int KS, int PADB, int PGn, bool NCHW_OUT>
__global__ __launch_bounds__(256)
void conv_shift(const f16* __restrict__ hin, const f16* __restrict__ apack,
                const float* __restrict__ bias, void* __restrict__ hout) {
  constexpr int SR = BR + 2;
  constexpr int ROWB = (W + 2) * PADB;
  __shared__ char smem[SR * ROWB];
  const int tid = threadIdx.x;
  const int n = blockIdx.y;
  const int r0 = blockIdx.x * BR;
  constexpr int CPC = C / 8;
  constexpr int TOTC = SR * (W + 2) * CPC;
  constexpr int NITER = (TOTC + 255) / 256;
  {
    float4 stg[NITER];
#pragma unroll
    for (int it = 0; it < NITER; ++it) {
      const int t = tid + it * 256;
      float4 v = make_float4(0.f, 0.f, 0.f, 0.f);
      if (t < TOTC) {
        int sr = t / ((W + 2) * CPC);
        int rem = t - sr * ((W + 2) * CPC);
        int px = rem / CPC;
        int kc = rem - px * CPC;
        int ri = r0 + sr - 1;
        int gx = px - 1;
        if (ri >= 0 && ri < H && gx >= 0 && gx < W)
          v = *(const float4*)(hin + (((size_t)(n * H + ri) * W + gx) * C + kc * 8));
      }
      stg[it] = v;
    }
#pragma unroll
    for (int it = 0; it < NITER; ++it) {
      const int t = tid + it * 256;
      if (t < TOTC) {
        int sr = t / ((W + 2) * CPC);
        int rem = t - sr * ((W + 2) * CPC);
        int px = rem / CPC;
        int kc = rem - px * CPC;
        *(float4*)(smem + sr * ROWB + px * PADB + kc * 16) = stg[it];
      }
    }
  }
  __syncthreads();

  const int wv = tid >> 6, l = tid & 63;
  constexpr int WPP = W / (16 * PGn);
  const int rp = wv / WPP;
  const int pxb = (wv % WPP) * 16 * PGn;
  const int rl0 = rp * 2;
  const int lp = l & 15, kg = l >> 4;
  const int px0 = pxb + lp;

  f32x4 acc[2][PGn][4];
#pragma unroll
  for (int a = 0; a < 2; ++a)
#pragma unroll
    for (int b = 0; b < PGn; ++b)
#pragma unroll
      for (int c = 0; c < 4; ++c)
        acc[a][b][c] = (f32x4){0.f, 0.f, 0.f, 0.f};

#pragma unroll
  for (int sh = 0; sh < 9; ++sh) {
    const int kh = sh / 3, kw = sh % 3;
    f16x8 A[KS][4];
#pragma unroll
    for (int ks = 0; ks < KS; ++ks)
#pragma unroll
      for (int og = 0; og < 4; ++og)
        A[ks][og] = *(const f16x8*)(apack + ((((sh * KS + ks) * 4 + og) << 9) + (l << 3)));
#pragma unroll
    for (int rowi = 0; rowi < 2; ++rowi) {
      const char* base = smem + (rl0 + rowi + kh) * ROWB;
#pragma unroll
      for (int pg = 0; pg < PGn; ++pg) {
#pragma unroll
        for (int ks = 0; ks < KS; ++ks) {
          f16x8 B = *(const f16x8*)(base + (px0 + pg * 16 + kw) * PADB + ks * 64 + kg * 16);
#pragma unroll
          for (int og = 0; og < 4; ++og)
            acc[rowi][pg][og] =
                __builtin_amdgcn_mfma_f32_16x16x32_f16(A[ks][og], B, acc[rowi][pg][og], 0, 0, 0);
        }
      }
    }
  }
  constexpr int PH = H / 2, PW = W / 2;
  const int pr = blockIdx.x * (BR / 2) + rp;
#pragma unroll
  for (int pg = 0; pg < PGn; ++pg) {
#pragma unroll
    for (int og = 0; og < 4; ++og) {
      float v[4];
#pragma unroll
      for (int c = 0; c < 4; ++c) {
        float m = fmaxf(acc[0][pg][og][c], acc[1][pg][og][c]);
        v[c] = fmaxf(m, __shfl_xor(m, 1));
      }
      if ((l & 1) == 0) {
        const int pw = (pxb + pg * 16 + lp) >> 1;
        const int oc0 = og * 16 + kg * 4;
        if constexpr (NCHW_OUT) {
          float* o = (float*)hout;
#pragma unroll
          for (int c = 0; c < 4; ++c)
            o[(((size_t)n * 64 + oc0 + c) * PH + pr) * PW + pw] =
                fmaxf(v[c] + bias[oc0 + c], 0.f);
        } else {
          f16x4 pk;
#pragma unroll
          for (int c = 0; c < 4; ++c)
            pk[c] = (f16)fmaxf(v[c] + bias[oc0 + c], 0.f);
          *(f16x4*)((f16*)hout + (((size_t)(n * PH + pr) * PW + pw) * 64 + oc0)) = pk;
        }
      }
    }
  }
}

// ---------------- FC head: wl1 in f16, 2 images/block, 8-way K-split ----------
// scan collapses: fx = h.(wl2[0]+20*wl2[2]) + bl2[0]+20*bl2[2]
__global__ __launch_bounds__(1024)
void fc_head(const float* __restrict__ h4, const f16* __restrict__ wl1h,
             const float* __restrict__ bl1, const float* __restrict__ wl2,
             const float* __restrict__ bl2, float* __restrict__ out) {
  __shared__ float rows[2][4096];
  __shared__ float red[8 * 128 * 2];
  __shared__ float red2[2 * 128];
  const int tid = threadIdx.x;
  const int b0 = blockIdx.x * 2;
  {
    const float4* src = (const float4*)(h4 + (size_t)b0 * 4096);
    float4* dst = (float4*)rows;
    for (int t = tid; t < 2048; t += 1024) dst[t] = src[t];
  }
  __syncthreads();

  const int nn = tid & 127;
  const int ks = tid >> 7;                 // 0..7, 512 K each
  const f16x8* wp = (const f16x8*)(wl1h + (size_t)nn * 4096 + ks * 512);
  const float4* x0 = (const float4*)(&rows[0][ks * 512]);
  const float4* x1 = (const float4*)(&rows[1][ks * 512]);
  float s0 = 0.f, s1 = 0.f;
#pragma unroll 4
  for (int i = 0; i < 64; ++i) {
    f16x8 w8 = wp[i];
    float4 a0 = x0[2 * i], a1 = x0[2 * i + 1];
    float4 b0 = x1[2 * i], b1 = x1[2 * i + 1];
    float w0 = (float)w8[0], w1 = (float)w8[1], w2 = (float)w8[2], w3 = (float)w8[3];
    float w4 = (float)w8[4], w5 = (float)w8[5], w6 = (float)w8[6], w7 = (float)w8[7];
    s0 = fmaf(w0, a0.x, fmaf(w1, a0.y, fmaf(w2, a0.z, fmaf(w3, a0.w, s0))));
    s0 = fmaf(w4, a1.x, fmaf(w5, a1.y, fmaf(w6, a1.z, fmaf(w7, a1.w, s0))));
    s1 = fmaf(w0, b0.x, fmaf(w1, b0.y, fmaf(w2, b0.z, fmaf(w3, b0.w, s1))));
    s1 = fmaf(w4, b1.x, fmaf(w5, b1.y, fmaf(w6, b1.z, fmaf(w7, b1.w, s1))));
  }
  red[(ks * 128 + nn) * 2 + 0] = s0;
  red[(ks * 128 + nn) * 2 + 1] = s1;
  __syncthreads();

  if (tid < 256) {
    const int r = tid >> 7, n2 = tid & 127;
    float h = bl1[n2];
#pragma unroll
    for (int k = 0; k < 8; ++k) h += red[(k * 128 + n2) * 2 + r];
    h = fmaxf(h, 0.f);
    red2[r * 128 + n2] = h * (wl2[n2] + 20.0f * wl2[256 + n2]);
  }
  __syncthreads();
#pragma unroll
  for (int s = 64; s > 0; s >>= 1) {
    if (tid < 2 * s) {
      int r = tid / s, i = tid - r * s;
      red2[r * 128 + i] += red2[r * 128 + i + s];
    }
    __syncthreads();
  }
  if (tid < 2) out[b0 + tid] = red2[tid * 128] + bl2[0] + 20.0f * bl2[2];
}

extern "C" void kernel_launch(void* const* d_in, const int* in_sizes, int n_in,
                              void* d_out, int out_size, void* d_ws, size_t ws_size,
                              hipStream_t stream) {
  const float* x   = (const float*)d_in[0];
  const float* w1  = (const float*)d_in[1];
  const float* b1  = (const float*)d_in[2];
  const float* w2  = (const float*)d_in[3];
  const float* b2  = (const float*)d_in[4];
  const float* w3  = (const float*)d_in[5];
  const float* b3  = (const float*)d_in[6];
  const float* w4  = (const float*)d_in[7];
  const float* b4  = (const float*)d_in[8];
  const float* wl1 = (const float*)d_in[9];
  const float* bl1 = (const float*)d_in[10];
  const float* wl2 = (const float*)d_in[11];
  const float* bl2 = (const float*)d_in[12];
  float* out = (float*)d_out;
  char* ws = (char*)d_ws;

  // ws layout: apack @0 (194KB); wl1h @512KB (1MB); h1 @2MB (64MB);
  // h2 @69206016 (32MB); h3 @102760448 (8MB); h4 @111149056 (4MB f32).
  f16* apack = (f16*)ws;
  f16* wl1h  = (f16*)(ws + 524288u);
  f16* h1 = (f16*)(ws + 2097152u);
  f16* h2 = (f16*)(ws + 69206016u);
  f16* h3 = (f16*)(ws + 102760448u);
  float* h4 = (float*)(ws + 111149056u);

  pack_weights<<<189, 512, 0, stream>>>(w1, w2, w3, w4, apack);
  pack_wl1<<<512, 256, 0, stream>>>(wl1, wl1h);
  conv1_mfma<<<dim3(4, 256), 512, 0, stream>>>(x, apack, b1, h1);
  conv2_roll<<<dim3(4, 256), 256, 0, stream>>>(h1, apack + 9 * 512, b2, h2);
  conv_shift32<64, 32, 32, 8, 144><<<dim3(4, 256), 256, 0, stream>>>(
      h2, apack + 45 * 512, b3, h3);
  conv_shift<64, 16, 16, 8, 2, 144, 1, true><<<dim3(2, 256), 256, 0, stream>>>(
      h3, apack + 117 * 512, b4, (void*)h4);
  fc_head<<<128, 1024, 0, stream>>>(h4, wl1h, bl1, wl2, bl2, out);
}

// Round 15
// 219.505 us; speedup vs baseline: 1.0627x; 1.0627x over previous
//
#include <hip/hip_runtime.h>

// MFMA f16 conv pipeline, round 15.
// Round-14 post-mortem: 3rd consecutive neutral; per-kernel profile hidden
// (all kernels < fillBuffer's 111us). Hypothesis fitting all nulls: time is
// spread over 7 serialized launches (dispatch+fill+drain ~8-15us each), not
// concentrated in inner loops. Fix: 7 -> 5 kernels. pack merged; conv4+fc
// fused per-image (h4 stays in LDS, never hits HBM).
//
// Layouts (CDNA4):
//   16x16x32: A/B k=(lane>>4)*8+j, m/n=lane&15; D col=lane&15, row=(lane>>4)*4+reg
//   32x32x16: A/B k=(lane>>5)*8+j, m/n=lane&31; D col=lane&31,
//             row=(reg&3)+8*(reg>>2)+4*(lane>>5)

typedef _Float16 f16;
typedef _Float16 f16x8 __attribute__((ext_vector_type(8)));
typedef _Float16 f16x4 __attribute__((ext_vector_type(4)));
typedef float f32x4 __attribute__((ext_vector_type(4)));
typedef float f32x16 __attribute__((ext_vector_type(16)));

// ---------------- pack_all: conv A-frags + wl1 -> f16 -------------------------
// blocks 0..188: apack frags (conv1 @0: 9; conv2 @9: 36; conv3 @45: 72;
// conv4 @117: 72). blocks 189..444: wl1 fp32 -> f16 (4 elems/thread).
__global__ __launch_bounds__(512)
void pack_all(const float* __restrict__ w1, const float* __restrict__ w2,
              const float* __restrict__ w3, const float* __restrict__ w4,
              const float* __restrict__ wl1, f16* __restrict__ apack,
              f16* __restrict__ wl1h) {
  if (blockIdx.x >= 189) {
    int i = ((blockIdx.x - 189) * 512 + threadIdx.x) * 4;   // 256 blocks
    float4 v = *(const float4*)(wl1 + i);
    f16x4 h = { (f16)v.x, (f16)v.y, (f16)v.z, (f16)v.w };
    *(f16x4*)(wl1h + i) = h;
    return;
  }
  int idx = blockIdx.x * 512 + threadIdx.x;
  int frag = idx >> 9;
  int e = idx & 511;
  int lane = e >> 3, j = e & 7;
  float v = 0.f;
  if (frag < 9) {
    int kh = frag / 3, kw = frag % 3;
    int oc = lane & 31;
    int ic = (lane >> 5) * 8 + j;
    if (ic < 12) v = w1[((oc * 12 + ic) * 3 + kh) * 3 + kw];
  } else if (frag < 45) {
    int f = frag - 9;            // conv2 32x32
    int ocg = f & 1;
    int sk = f >> 1;
    int ks = sk & 1, sh = sk >> 1;
    int kh = sh / 3, kw = sh % 3;
    int oc = ocg * 32 + (lane & 31);
    int ic = ks * 16 + (lane >> 5) * 8 + j;
    v = w2[((oc * 32 + ic) * 3 + kh) * 3 + kw];
  } else if (frag < 117) {
    int f = frag - 45;           // conv3 32x32
    int ocg = f & 1;
    int sk = f >> 1;
    int ks = sk & 3, sh = sk >> 2;
    int kh = sh / 3, kw = sh % 3;
    int oc = ocg * 32 + (lane & 31);
    int ic = ks * 16 + (lane >> 5) * 8 + j;
    v = w3[((oc * 64 + ic) * 3 + kh) * 3 + kw];
  } else {
    int f = frag - 117;          // conv4 16x16
    int sk = f >> 2, og = f & 3;
    int sh = sk >> 1, ks = sk & 1;
    int kh = sh / 3, kw = sh % 3;
    int row16 = lane & 15, kg = lane >> 4;
    int oc = og * 16 + row16;
    int ic = ks * 32 + kg * 8 + j;
    v = w4[((oc * 64 + ic) * 3 + kh) * 3 + kw];
  }
  apack[idx] = (f16)v;
}

// ---------------- conv1: 12ch fp32 NCHW -> 32ch NHWC f16, pool ----------------
// (unchanged: TPB=8 rolling 6-slot window, 32x32x16, kw-outer B-share)
__global__ __launch_bounds__(512)
void conv1_mfma(const float* __restrict__ x, const f16* __restrict__ apack,
                const float* __restrict__ bias, f16* __restrict__ hout) {
  constexpr int W = 128, H = 128;
  constexpr int PADB = 48, ROWB = 130 * PADB;
  constexpr int TPB = 8;
  __shared__ char smem[6 * ROWB];               // 37440 B
  const int tid = threadIdx.x;
  const int n = blockIdx.y;
  const int R0 = blockIdx.x * (TPB * 4);

  if (tid < 36) {
    int slot = tid / 6, r = tid % 6;
    int px = (r >= 3) ? 129 : 0;
    int ch = r % 3;
    *(float4*)(smem + slot * ROWB + px * PADB + ch * 16) =
        make_float4(0.f, 0.f, 0.f, 0.f);
  }

  const int g = tid >> 4;
  const int l16 = tid & 15;
  const int Q = l16 >> 2, q = l16 & 3;

  auto load_row = [&](int ri) -> float4 {
    float4 v = make_float4(0.f, 0.f, 0.f, 0.f);
    if (l16 < 12 && ri >= 0 && ri < H)
      v = *(const float4*)(x + ((size_t)(n * 12 + l16) * H + ri) * W + g * 4);
    return v;
  };
  auto xpose_write = [&](float4 av, int slot) {
    float4 t1, t2;
    {
      float sx = __shfl_xor(av.x, 1), sy = __shfl_xor(av.y, 1);
      float sz = __shfl_xor(av.z, 1), sw = __shfl_xor(av.w, 1);
      bool odd = q & 1;
      t1.x = odd ? sy : av.x;  t1.y = odd ? av.y : sx;
      t1.z = odd ? sw : av.z;  t1.w = odd ? av.w : sz;
    }
    {
      float sx = __shfl_xor(t1.x, 2), sy = __shfl_xor(t1.y, 2);
      float sz = __shfl_xor(t1.z, 2), sw = __shfl_xor(t1.w, 2);
      bool hi2 = q & 2;
      t2.x = hi2 ? sz : t1.x;  t2.y = hi2 ? sw : t1.y;
      t2.z = hi2 ? t1.z : sx;  t2.w = hi2 ? t1.w : sy;
    }
    f16x4 h = { (f16)t2.x, (f16)t2.y, (f16)t2.z, (f16)t2.w };
    *(f16x4*)(smem + slot * ROWB + (g * 4 + q + 1) * PADB + Q * 8) = h;
  };

  const int wv = tid >> 6, l = tid & 63;
  const int rp = wv >> 2;
  const int pxb = (wv & 3) * 32;
  const int rl0 = rp * 2;
  const int ln = l & 31;
  const int hi = l >> 5;

  f16x8 A[9];
#pragma unroll
  for (int ks = 0; ks < 9; ++ks)
    A[ks] = *(const f16x8*)(apack + ((ks << 9) + (l << 3)));

  float4 a[6];
#pragma unroll
  for (int i = 0; i < 6; ++i) a[i] = load_row(R0 - 1 + i);
#pragma unroll
  for (int i = 0; i < 6; ++i) xpose_write(a[i], i);
  __syncthreads();

  int s0 = 0;
  for (int t = 0; t < TPB; ++t) {
    if (t + 1 < TPB) {
#pragma unroll
      for (int i = 0; i < 4; ++i) a[i] = load_row(R0 + 4 * t + 5 + i);
    }
    f32x16 acc0 = (f32x16)0.f, acc1 = (f32x16)0.f;
#pragma unroll
    for (int kw = 0; kw < 3; ++kw) {
      const char* bcol = smem + (pxb + ln + kw) * PADB + hi * 16;
      f16x8 R[4];
#pragma unroll
      for (int j = 0; j < 4; ++j) {
        int sl = s0 + rl0 + j; if (sl >= 6) sl -= 6;
        R[j] = *(const f16x8*)(bcol + sl * ROWB);
      }
#pragma unroll
      for (int kh = 0; kh < 3; ++kh) {
        acc0 = __builtin_amdgcn_mfma_f32_32x32x16_f16(A[kh * 3 + kw], R[kh],     acc0, 0, 0, 0);
        acc1 = __builtin_amdgcn_mfma_f32_32x32x16_f16(A[kh * 3 + kw], R[kh + 1], acc1, 0, 0, 0);
      }
    }
    {
      const int pr = (R0 >> 1) + 2 * t + rp;
#pragma unroll
      for (int gg = 0; gg < 4; ++gg) {
        float v[4];
#pragma unroll
        for (int c = 0; c < 4; ++c) {
          float m = fmaxf(acc0[gg * 4 + c], acc1[gg * 4 + c]);
          v[c] = fmaxf(m, __shfl_xor(m, 1));
        }
        if ((l & 1) == 0) {
          const int pw = (pxb + ln) >> 1;
          const int oc0 = gg * 8 + hi * 4;
          f16x4 pk;
#pragma unroll
          for (int c = 0; c < 4; ++c)
            pk[c] = (f16)fmaxf(v[c] + bias[oc0 + c], 0.f);
          *(f16x4*)(hout + (((size_t)(n * 64 + pr) * 64 + pw) * 32 + oc0)) = pk;
        }
      }
    }
    __syncthreads();
    if (t + 1 < TPB) {
#pragma unroll
      for (int i = 0; i < 4; ++i) {
        int sl = s0 + i; if (sl >= 6) sl -= 6;
        xpose_write(a[i], sl);
      }
      __syncthreads();
    }
    s0 += 4; if (s0 >= 6) s0 -= 6;
  }
}

// ---------------- conv2: rolling-window multi-tile, 32x32x16 ------------------
__global__ __launch_bounds__(256)
void conv2_roll(const f16* __restrict__ hin, const f16* __restrict__ apack,
                const float* __restrict__ bias, f16* __restrict__ hout) {
  constexpr int C = 32, W = 64, H = 64;
  constexpr int PADB = 80, ROWB = 66 * PADB;
  constexpr int TPB = 4;
  __shared__ char smem[6 * ROWB];               // 31680 B
  const int tid = threadIdx.x;
  const int n = blockIdx.y;
  const int R0 = blockIdx.x * (TPB * 4);

  auto chunk_ld = [&](int c, int rbase) -> float4 {
    int rowl = c / 264, rem = c - rowl * 264;
    int px = rem >> 2, kc = rem & 3;
    int ri = rbase + rowl, gx = px - 1;
    float4 v = make_float4(0.f, 0.f, 0.f, 0.f);
    if (ri >= 0 && ri < H && gx >= 0 && gx < W)
      v = *(const float4*)(hin + (((size_t)(n * H + ri) * W + gx) * C + kc * 8));
    return v;
  };
  auto chunk_st = [&](int c, int sbase, float4 v) {
    int rowl = c / 264, rem = c - rowl * 264;
    int px = rem >> 2, kc = rem & 3;
    int slot = sbase + rowl; if (slot >= 6) slot -= 6;
    *(float4*)(smem + slot * ROWB + px * PADB + kc * 16) = v;
  };

  {
    float4 a[7];
#pragma unroll
    for (int it = 0; it < 7; ++it) {
      int c = tid + it * 256;
      a[it] = (c < 1584) ? chunk_ld(c, R0 - 1) : make_float4(0.f, 0.f, 0.f, 0.f);
    }
#pragma unroll
    for (int it = 0; it < 7; ++it) {
      int c = tid + it * 256;
      if (c < 1584) chunk_st(c, 0, a[it]);
    }
  }
  __syncthreads();

  const int wv = tid >> 6, l = tid & 63;
  const int rp = wv >> 1;
  const int pxb = (wv & 1) * 32;
  const int rl0 = rp * 2;
  const int ln = l & 31;
  const int hi = l >> 5;

  float4 a[5];
  int s04 = 0;
  for (int t = 0; t < TPB; ++t) {
    if (t + 1 < TPB) {
#pragma unroll
      for (int it = 0; it < 5; ++it) {
        int c = tid + it * 256;
        a[it] = (c < 1056) ? chunk_ld(c, R0 + 4 * t + 5)
                           : make_float4(0.f, 0.f, 0.f, 0.f);
      }
    }
    f32x16 acc[2][2];
    acc[0][0] = (f32x16)0.f; acc[0][1] = (f32x16)0.f;
    acc[1][0] = (f32x16)0.f; acc[1][1] = (f32x16)0.f;
#pragma unroll
    for (int sh = 0; sh < 9; ++sh) {
      const int kh = sh / 3, kw = sh % 3;
      f16x8 A[2][2];
#pragma unroll
      for (int ks = 0; ks < 2; ++ks)
#pragma unroll
        for (int ocg = 0; ocg < 2; ++ocg)
          A[ks][ocg] = *(const f16x8*)(apack + ((((sh * 2 + ks) * 2 + ocg) << 9) + (l << 3)));
#pragma unroll
      for (int rowi = 0; rowi < 2; ++rowi) {
        int sl = s04 + rl0 + rowi + kh; if (sl >= 6) sl -= 6;
        const char* base = smem + sl * ROWB + (pxb + ln + kw) * PADB + hi * 16;
#pragma unroll
        for (int ks = 0; ks < 2; ++ks) {
          f16x8 B = *(const f16x8*)(base + ks * 32);
          acc[rowi][0] = __builtin_amdgcn_mfma_f32_32x32x16_f16(A[ks][0], B, acc[rowi][0], 0, 0, 0);
          acc[rowi][1] = __builtin_amdgcn_mfma_f32_32x32x16_f16(A[ks][1], B, acc[rowi][1], 0, 0, 0);
        }
      }
    }
    {
      const int pr = (R0 >> 1) + 2 * t + rp;
#pragma unroll
      for (int ocg = 0; ocg < 2; ++ocg) {
#pragma unroll
        for (int gg = 0; gg < 4; ++gg) {
          float v[4];
#pragma unroll
          for (int c = 0; c < 4; ++c) {
            float m = fmaxf(acc[0][ocg][gg * 4 + c], acc[1][ocg][gg * 4 + c]);
            v[c] = fmaxf(m, __shfl_xor(m, 1));
          }
          if ((l & 1) == 0) {
            const int pw = (pxb + ln) >> 1;
            const int oc0 = ocg * 32 + gg * 8 + hi * 4;
            f16x4 pk;
#pragma unroll
            for (int c = 0; c < 4; ++c)
              pk[c] = (f16)fmaxf(v[c] + bias[oc0 + c], 0.f);
            *(f16x4*)(hout + (((size_t)(n * 32 + pr) * 32 + pw) * 64 + oc0)) = pk;
          }
        }
      }
    }
    __syncthreads();
    if (t + 1 < TPB) {
#pragma unroll
      for (int it = 0; it < 5; ++it) {
        int c = tid + it * 256;
        if (c < 1056) chunk_st(c, s04, a[it]);
      }
      __syncthreads();
    }
    s04 += 4; if (s04 >= 6) s04 -= 6;
  }
}

// ---------------- conv3: one-shot 32x32x16 ------------------------------------
template<int C, int W, int H, int BR, int PADB>
__global__ __launch_bounds__(256)
void conv_shift32(const f16* __restrict__ hin, const f16* __restrict__ apack,
                  const float* __restrict__ bias, f16* __restrict__ hout) {
  constexpr int KS16 = C / 16;
  constexpr int SR = BR + 2;
  constexpr int ROWB = (W + 2) * PADB;
  __shared__ char smem[SR * ROWB];
  const int tid = threadIdx.x;
  const int n = blockIdx.y;
  const int r0 = blockIdx.x * BR;
  constexpr int CPC = C / 8;
  constexpr int TOTC = SR * (W + 2) * CPC;
  constexpr int NITER = (TOTC + 255) / 256;
  {
    float4 stg[NITER];
#pragma unroll
    for (int it = 0; it < NITER; ++it) {
      const int t = tid + it * 256;
      float4 v = make_float4(0.f, 0.f, 0.f, 0.f);
      if (t < TOTC) {
        int sr = t / ((W + 2) * CPC);
        int rem = t - sr * ((W + 2) * CPC);
        int px = rem / CPC;
        int kc = rem - px * CPC;
        int ri = r0 + sr - 1;
        int gx = px - 1;
        if (ri >= 0 && ri < H && gx >= 0 && gx < W)
          v = *(const float4*)(hin + (((size_t)(n * H + ri) * W + gx) * C + kc * 8));
      }
      stg[it] = v;
    }
#pragma unroll
    for (int it = 0; it < NITER; ++it) {
      const int t = tid + it * 256;
      if (t < TOTC) {
        int sr = t / ((W + 2) * CPC);
        int rem = t - sr * ((W + 2) * CPC);
        int px = rem / CPC;
        int kc = rem - px * CPC;
        *(float4*)(smem + sr * ROWB + px * PADB + kc * 16) = stg[it];
      }
    }
  }
  __syncthreads();

  const int wv = tid >> 6, l = tid & 63;
  constexpr int WPP = W / 32;
  const int rp = wv / WPP;
  const int pxb = (wv % WPP) * 32;
  const int rl0 = rp * 2;
  const int ln = l & 31;
  const int hi = l >> 5;
  const int px0 = pxb + ln;

  f32x16 acc[2][2];
  acc[0][0] = (f32x16)0.f; acc[0][1] = (f32x16)0.f;
  acc[1][0] = (f32x16)0.f; acc[1][1] = (f32x16)0.f;

#pragma unroll
  for (int sh = 0; sh < 9; ++sh) {
    const int kh = sh / 3, kw = sh % 3;
    f16x8 A[KS16][2];
#pragma unroll
    for (int ks = 0; ks < KS16; ++ks)
#pragma unroll
      for (int ocg = 0; ocg < 2; ++ocg)
        A[ks][ocg] = *(const f16x8*)(apack + ((((sh * KS16 + ks) * 2 + ocg) << 9) + (l << 3)));
#pragma unroll
    for (int rowi = 0; rowi < 2; ++rowi) {
      const char* base = smem + (rl0 + rowi + kh) * ROWB + (px0 + kw) * PADB + hi * 16;
#pragma unroll
      for (int ks = 0; ks < KS16; ++ks) {
        f16x8 B = *(const f16x8*)(base + ks * 32);
        acc[rowi][0] = __builtin_amdgcn_mfma_f32_32x32x16_f16(A[ks][0], B, acc[rowi][0], 0, 0, 0);
        acc[rowi][1] = __builtin_amdgcn_mfma_f32_32x32x16_f16(A[ks][1], B, acc[rowi][1], 0, 0, 0);
      }
    }
  }
  constexpr int PH = H / 2, PW = W / 2;
  const int pr = blockIdx.x * (BR / 2) + rp;
#pragma unroll
  for (int ocg = 0; ocg < 2; ++ocg) {
#pragma unroll
    for (int gg = 0; gg < 4; ++gg) {
      float v[4];
#pragma unroll
      for (int c = 0; c < 4; ++c) {
        float m = fmaxf(acc[0][ocg][gg * 4 + c], acc[1][ocg][gg * 4 + c]);
        v[c] = fmaxf(m, __shfl_xor(m, 1));
      }
      if ((l & 1) == 0) {
        const int pw = (pxb + ln) >> 1;
        const int oc0 = ocg * 32 + gg * 8 + hi * 4;
        f16x4 pk;
#pragma unroll
        for (int c = 0; c < 4; ++c)
          pk[c] = (f16)fmaxf(v[c] + bias[oc0 + c], 0.f);
        *(f16x4*)(hout + (((size_t)(n * PH + pr) * PW + pw) * 64 + oc0)) = pk;
      }
    }
  }
}

// ---------------- tail_fused: conv4 + maxpool + FC head, one block per image --
// Stage h3 (18x18x64 halo tile) -> conv4 16x16x32 MFMA -> pooled h4 into LDS
// hbuf[k] (k = oc*64 + pr*8 + pw, the NCHW reshape order) -> FC1(f16 wl1)+ReLU
// -> collapsed scan: out = h.(wl2[0]+20*wl2[2]) + bl2[0]+20*bl2[2].
__global__ __launch_bounds__(512)
void tail_fused(const f16* __restrict__ hin, const f16* __restrict__ apack4,
                const float* __restrict__ bias, const f16* __restrict__ wl1h,
                const float* __restrict__ bl1, const float* __restrict__ wl2,
                const float* __restrict__ bl2, float* __restrict__ out) {
  constexpr int C = 64, W = 16, H = 16;
  constexpr int PADB = 144, ROWB = 18 * PADB;   // 2592 B/row-slot
  __shared__ char smem[18 * ROWB];              // 46656 B
  __shared__ float hbuf[4096];
  __shared__ float red[4 * 128];
  __shared__ float red2[128];
  const int tid = threadIdx.x;
  const int n = blockIdx.x;

  // ---- stage h3 image with halo: 18 slots x 18 px x 8 chunks = 2592 ----
  constexpr int CPC = 8, TOTC = 18 * 18 * CPC;
  {
    float4 stg[6];
#pragma unroll
    for (int it = 0; it < 6; ++it) {
      const int t = tid + it * 512;
      float4 v = make_float4(0.f, 0.f, 0.f, 0.f);
      if (t < TOTC) {
        int sr = t / (18 * CPC);
        int rem = t - sr * (18 * CPC);
        int px = rem / CPC;
        int kc = rem - px * CPC;
        int ri = sr - 1, gx = px - 1;
        if (ri >= 0 && ri < H && gx >= 0 && gx < W)
          v = *(const float4*)(hin + (((size_t)(n * H + ri) * W + gx) * C + kc * 8));
      }
      stg[it] = v;
    }
#pragma unroll
    for (int it = 0; it < 6; ++it) {
      const int t = tid + it * 512;
      if (t < TOTC) {
        int sr = t / (18 * CPC);
        int rem = t - sr * (18 * CPC);
        int px = rem / CPC;
        int kc = rem - px * CPC;
        *(float4*)(smem + sr * ROWB + px * PADB + kc * 16) = stg[it];
      }
    }
  }
  __syncthreads();

  // ---- conv4: 8 waves, wave wv = pooled row (conv rows 2wv, 2wv+1) ----
  {
    const int wv = tid >> 6, l = tid & 63;
    const int lp = l & 15, kg = l >> 4;
    const int rl0 = wv * 2;

    f32x4 acc[2][4];
#pragma unroll
    for (int a = 0; a < 2; ++a)
#pragma unroll
      for (int o = 0; o < 4; ++o) acc[a][o] = (f32x4){0.f, 0.f, 0.f, 0.f};

#pragma unroll
    for (int sh = 0; sh < 9; ++sh) {
      const int kh = sh / 3, kw = sh % 3;
      f16x8 A[2][4];
#pragma unroll
      for (int ks = 0; ks < 2; ++ks)
#pragma unroll
        for (int og = 0; og < 4; ++og)
          A[ks][og] = *(const f16x8*)(apack4 + ((((sh * 2 + ks) * 4 + og) << 9) + (l << 3)));
#pragma unroll
      for (int rowi = 0; rowi < 2; ++rowi) {
        const char* base = smem + (rl0 + rowi + kh) * ROWB;
#pragma unroll
        for (int ks = 0; ks < 2; ++ks) {
          f16x8 B = *(const f16x8*)(base + (lp + kw) * PADB + ks * 64 + kg * 16);
#pragma unroll
          for (int og = 0; og < 4; ++og)
            acc[rowi][og] =
                __builtin_amdgcn_mfma_f32_16x16x32_f16(A[ks][og], B, acc[rowi][og], 0, 0, 0);
        }
      }
    }
    // pool + bias + relu -> hbuf[k], k = oc*64 + pr*8 + pw
#pragma unroll
    for (int og = 0; og < 4; ++og) {
      float v[4];
#pragma unroll
      for (int c = 0; c < 4; ++c) {
        float m = fmaxf(acc[0][og][c], acc[1][og][c]);
        v[c] = fmaxf(m, __shfl_xor(m, 1));
      }
      if ((l & 1) == 0) {
        const int pw = lp >> 1;
        const int oc0 = og * 16 + kg * 4;
#pragma unroll
        for (int c = 0; c < 4; ++c)
          hbuf[(oc0 + c) * 64 + wv * 8 + pw] = fmaxf(v[c] + bias[oc0 + c], 0.f);
      }
    }
  }
  __syncthreads();

  // ---- FC head: 512 thr = 128 neurons x 4 k-slices of 1024 ----
  {
    const int nn = tid & 127;
    const int ks = tid >> 7;
    const f16x8* wp = (const f16x8*)(wl1h + (size_t)nn * 4096 + ks * 1024);
    const float4* xr = (const float4*)(&hbuf[ks * 1024]);
    float s = 0.f;
#pragma unroll 4
    for (int i = 0; i < 128; ++i) {
      f16x8 w8 = wp[i];
      float4 a0 = xr[2 * i], a1 = xr[2 * i + 1];
      s = fmaf((float)w8[0], a0.x, fmaf((float)w8[1], a0.y,
          fmaf((float)w8[2], a0.z, fmaf((float)w8[3], a0.w, s))));
      s = fmaf((float)w8[4], a1.x, fmaf((float)w8[5], a1.y,
          fmaf((float)w8[6], a1.z, fmaf((float)w8[7], a1.w, s))));
    }
    red[ks * 128 + nn] = s;
  }
  __syncthreads();
  if (tid < 128) {
    float h = bl1[tid] + red[tid] + red[128 + tid] + red[256 + tid] + red[384 + tid];
    h = fmaxf(h, 0.f);
    red2[tid] = h * (wl2[tid] + 20.0f * wl2[256 + tid]);
  }
  __syncthreads();
#pragma unroll
  for (int s = 64; s > 0; s >>= 1) {
    if (tid < s) red2[tid] += red2[tid + s];
    __syncthreads();
  }
  if (tid == 0) out[n] = red2[0] + bl2[0] + 20.0f * bl2[2];
}

extern "C" void kernel_launch(void* const* d_in, const int* in_sizes, int n_in,
                              void* d_out, int out_size, void* d_ws, size_t ws_size,
                              hipStream_t stream) {
  const float* x   = (const float*)d_in[0];
  const float* w1  = (const float*)d_in[1];
  const float* b1  = (const float*)d_in[2];
  const float* w2  = (const float*)d_in[3];
  const float* b2  = (const float*)d_in[4];
  const float* w3  = (const float*)d_in[5];
  const float* b3  = (const float*)d_in[6];
  const float* w4  = (const float*)d_in[7];
  const float* b4  = (const float*)d_in[8];
  const float* wl1 = (const float*)d_in[9];
  const float* bl1 = (const float*)d_in[10];
  const float* wl2 = (const float*)d_in[11];
  const float* bl2 = (const float*)d_in[12];
  float* out = (float*)d_out;
  char* ws = (char*)d_ws;

  // ws layout: apack @0 (194KB); wl1h @512KB (1MB); h1 @2MB (64MB);
  // h2 @69206016 (32MB); h3 @102760448 (8MB).
  f16* apack = (f16*)ws;
  f16* wl1h  = (f16*)(ws + 524288u);
  f16* h1 = (f16*)(ws + 2097152u);
  f16* h2 = (f16*)(ws + 69206016u);
  f16* h3 = (f16*)(ws + 102760448u);

  pack_all<<<445, 512, 0, stream>>>(w1, w2, w3, w4, wl1, apack, wl1h);
  conv1_mfma<<<dim3(4, 256), 512, 0, stream>>>(x, apack, b1, h1);
  conv2_roll<<<dim3(4, 256), 256, 0, stream>>>(h1, apack + 9 * 512, b2, h2);
  conv_shift32<64, 32, 32, 8, 144><<<dim3(4, 256), 256, 0, stream>>>(
      h2, apack + 45 * 512, b3, h3);
  tail_fused<<<256, 512, 0, stream>>>(h3, apack + 117 * 512, b4, wl1h,
                                      bl1, wl2, bl2, out);
}